// Round 6
// baseline (114.272 us; speedup 1.0000x reference)
//
#include <hip/hip_runtime.h>
#include <hip/hip_bf16.h>

typedef __attribute__((ext_vector_type(8))) short bf16x8;   // 8 bf16 (MFMA A/B frag)
typedef __attribute__((ext_vector_type(4))) float f32x4;    // MFMA C/D frag

static __device__ __forceinline__ unsigned short f2b(float f) {
  union { __hip_bfloat16 h; unsigned short u; } cv;
  cv.h = __float2bfloat16(f);
  return cv.u;
}

static __device__ __forceinline__ bf16x8 pack8(float4 a, float4 b) {
  bf16x8 r;
  r[0] = (short)f2b(a.x); r[1] = (short)f2b(a.y); r[2] = (short)f2b(a.z); r[3] = (short)f2b(a.w);
  r[4] = (short)f2b(b.x); r[5] = (short)f2b(b.y); r[6] = (short)f2b(b.z); r[7] = (short)f2b(b.w);
  return r;
}

// ---- prep: weights -> bf16 W^T in ws ----
// wt layout (bf16 elems): WT1 @0 (256x128), WT2 @32768 (256x256), WT3 @98304 (256x256)
__global__ void __launch_bounds__(256) gnn_prep(const float* __restrict__ W1,
                                                const float* __restrict__ W2,
                                                const float* __restrict__ W3,
                                                unsigned short* __restrict__ wt) {
  int idx = blockIdx.x * 256 + threadIdx.x;   // 0..65535
  unsigned short* wt1 = wt;
  unsigned short* wt2 = wt + 32768;
  unsigned short* wt3 = wt + 98304;
  if (idx < 32768) { int d = idx >> 8, h = idx & 255; wt1[h * 128 + d] = f2b(W1[idx]); }
  { int d = idx >> 8, h = idx & 255; wt2[h * 256 + d] = f2b(W2[idx]); wt3[h * 256 + d] = f2b(W3[idx]); }
}

// ---- main: one block per graph, 1024 thr (16 waves), 128 KB LDS, 1 block/CU ----
// Full-layer phases: A-phase writes ALL of sAgg (1 barrier), B-phase runs full-K matmul
// (1 barrier). ~8 barriers total vs ~22 chunked. Swizzles: 16B granule XOR'd with low
// row bits, applied identically on write and read (conflict-free per 16-lane quarter).
#define XS(d, colb) ((d) * 128 + ((((colb) ^ (((d) & 15) << 4))) >> 1))
#define AG2(i, colb) ((i) * 256 + ((((colb) ^ (((i) & 15) << 4))) >> 1))

__global__ void __launch_bounds__(1024, 4) gnn_main(
    const float* __restrict__ xin, const float* __restrict__ adjg,
    const float* __restrict__ b1, const float* __restrict__ b2,
    const float* __restrict__ b3, const float* __restrict__ Wh,
    const float* __restrict__ bh, const unsigned short* __restrict__ wt,
    float* __restrict__ out) {
  __shared__ unsigned short sXT[256 * 128];    // X^T [d][j], swizzled; 64 KB
  __shared__ unsigned short sAgg[128 * 256];   // AGG [i][d] full layer, swizzled; 64 KB

  const int g = blockIdx.x, tid = threadIdx.x;
  const int lane = tid & 63, w = tid >> 6;     // 16 waves
  const int l15 = lane & 15, l4 = lane >> 4;
  const int wm = w & 1;    // A-phase: d-half of this i-slice
  const int wi = w >> 1;   // A-phase: i-slice (0..7)
  const int wr = w & 3;    // B-phase: i-group (0..3)
  const int wc = w >> 2;   // B-phase: h-group (0..3)

  const float* xg = xin + (size_t)g * 16384;
  const float* ag = adjg + (size_t)g * 16384;

  // ---- adj B-fragments: wave covers i in [wi*16, wi*16+16); loaded once, 16 regs ----
  // (adjacency is layer-invariant AND symmetric: adj[j][i] read as rows adj[i][j])
  bf16x8 adjF[4];
  {
    int ir = wi * 16 + l15;
#pragma unroll
    for (int ks = 0; ks < 4; ++ks) {
      float4 a0 = *(const float4*)(ag + ir * 128 + ks * 32 + l4 * 8);
      float4 a1 = *(const float4*)(ag + ir * 128 + ks * 32 + l4 * 8 + 4);
      adjF[ks] = pack8(a0, a1);
    }
  }
  // ---- in-kernel X transpose: X[j][d] fp32 -> sXT[d][j] bf16 (4x4 register-blocked) ----
  {
    int db = tid & 31, jb = tid >> 5;          // 32 d-blocks x 32 j-blocks
    int d0 = db * 4, j0 = jb * 4;
    float4 r0 = *(const float4*)(xg + (j0 + 0) * 128 + d0);
    float4 r1 = *(const float4*)(xg + (j0 + 1) * 128 + d0);
    float4 r2 = *(const float4*)(xg + (j0 + 2) * 128 + d0);
    float4 r3 = *(const float4*)(xg + (j0 + 3) * 128 + d0);
    *(ushort4*)&sXT[XS(d0 + 0, j0 * 2)] = make_ushort4(f2b(r0.x), f2b(r1.x), f2b(r2.x), f2b(r3.x));
    *(ushort4*)&sXT[XS(d0 + 1, j0 * 2)] = make_ushort4(f2b(r0.y), f2b(r1.y), f2b(r2.y), f2b(r3.y));
    *(ushort4*)&sXT[XS(d0 + 2, j0 * 2)] = make_ushort4(f2b(r0.z), f2b(r1.z), f2b(r2.z), f2b(r3.z));
    *(ushort4*)&sXT[XS(d0 + 3, j0 * 2)] = make_ushort4(f2b(r0.w), f2b(r1.w), f2b(r2.w), f2b(r3.w));
  }
  __syncthreads();

  for (int l = 0; l < 3; ++l) {
    const int Din = (l == 0) ? 128 : 256;
    const int tpw = Din >> 5;                  // d-tiles per wave in A-phase (4 or 8)
    const unsigned short* wtl = (l == 0) ? wt : (l == 1) ? wt + 32768 : wt + 98304;

    // ---- phase A (full): AGG^T[d][i] = sum_j X^T[d][j]*adj[j][i], K=128 always ----
    // wave (wm,wi): d-tiles [wm*tpw, wm*tpw+tpw) for i-slice wi; batches of 4 tiles
#pragma unroll
    for (int b = 0; b < 2; ++b) {
      if (b < (tpw >> 2)) {
        f32x4 accA[4];
#pragma unroll
        for (int t = 0; t < 4; ++t) accA[t] = (f32x4){0.f, 0.f, 0.f, 0.f};
#pragma unroll
        for (int ks = 0; ks < 4; ++ks) {
          bf16x8 a[4];
#pragma unroll
          for (int t = 0; t < 4; ++t) {
            int dr = (wm * tpw + b * 4 + t) * 16 + l15;
            a[t] = *(const bf16x8*)&sXT[XS(dr, ks * 64 + l4 * 16)];
          }
#pragma unroll
          for (int t = 0; t < 4; ++t)
            accA[t] = __builtin_amdgcn_mfma_f32_16x16x32_bf16(a[t], adjF[ks], accA[t], 0, 0, 0);
        }
        int i = wi * 16 + l15;
#pragma unroll
        for (int t = 0; t < 4; ++t) {
          int dloc = (wm * tpw + b * 4 + t) * 16 + l4 * 4;
          f32x4 v = accA[t];
          *(ushort4*)&sAgg[AG2(i, 2 * dloc)] =
              make_ushort4(f2b(v[0]), f2b(v[1]), f2b(v[2]), f2b(v[3]));
        }
      }
    }
    __syncthreads();

    // ---- phase B (full K): H[i][h] = AGG[i][:] @ W[:][h]; wave grid 4(i) x 4(h) ----
    f32x4 accB[2][4];
#pragma unroll
    for (int mi = 0; mi < 2; ++mi)
#pragma unroll
      for (int ni = 0; ni < 4; ++ni) accB[mi][ni] = (f32x4){0.f, 0.f, 0.f, 0.f};

#pragma unroll
    for (int ks = 0; ks < 8; ++ks) {
      if (ks < (Din >> 5)) {
        bf16x8 aB[2];
#pragma unroll
        for (int mi = 0; mi < 2; ++mi) {
          int ir = wr * 32 + mi * 16 + l15;
          aB[mi] = *(const bf16x8*)&sAgg[AG2(ir, ks * 64 + l4 * 16)];
        }
#pragma unroll
        for (int ni = 0; ni < 4; ++ni) {
          int hr = wc * 64 + ni * 16 + l15;
          bf16x8 wf = *(const bf16x8*)(wtl + hr * Din + ks * 32 + l4 * 8);
#pragma unroll
          for (int mi = 0; mi < 2; ++mi)
            accB[mi][ni] = __builtin_amdgcn_mfma_f32_16x16x32_bf16(aB[mi], wf, accB[mi][ni], 0, 0, 0);
        }
      }
    }

    if (l < 2) {
      const float* bl = (l == 0) ? b1 : b2;
      // H[i][h] -> sXT[h][i] (next layer's X^T), 8B swizzled writes
      // (safe: all sXT reads finished before the post-A barrier)
#pragma unroll
      for (int ni = 0; ni < 4; ++ni) {
        int h = wc * 64 + ni * 16 + l15;
        float bias = bl[h];
#pragma unroll
        for (int mi = 0; mi < 2; ++mi) {
          int i0 = wr * 32 + mi * 16 + l4 * 4;
          f32x4 v = accB[mi][ni];
          *(ushort4*)&sXT[XS(h, 2 * i0)] = make_ushort4(
              f2b(fmaxf(v[0] + bias, 0.f)), f2b(fmaxf(v[1] + bias, 0.f)),
              f2b(fmaxf(v[2] + bias, 0.f)), f2b(fmaxf(v[3] + bias, 0.f)));
        }
      }
      __syncthreads();
    } else {
      // ---- mean pool + linear head (fp32) ----
      __syncthreads();                // all waves done READING sAgg before aliasing it
      float* sPool = (float*)sAgg;    // [4 wr][256 h]
      float ps[4];
#pragma unroll
      for (int ni = 0; ni < 4; ++ni) {
        float bias = b3[wc * 64 + ni * 16 + l15];
        float s = 0.f;
#pragma unroll
        for (int mi = 0; mi < 2; ++mi)
#pragma unroll
          for (int r = 0; r < 4; ++r) s += fmaxf(accB[mi][ni][r] + bias, 0.f);
        s += __shfl_xor(s, 16);   // reduce over l4 bit 0
        s += __shfl_xor(s, 32);   // reduce over l4 bit 1
        ps[ni] = s;
      }
      if (l4 == 0) {
#pragma unroll
        for (int ni = 0; ni < 4; ++ni)
          sPool[wr * 256 + wc * 64 + ni * 16 + l15] = ps[ni];
      }
      __syncthreads();
      if (w == 0) {
        float acc = 0.f;
#pragma unroll
        for (int q = 0; q < 4; ++q) {
          int h = lane + q * 64;
          float p = sPool[h] + sPool[256 + h] + sPool[512 + h] + sPool[768 + h];
          acc += p * Wh[h];
        }
#pragma unroll
        for (int off = 32; off > 0; off >>= 1) acc += __shfl_xor(acc, off);
        if (lane == 0) out[g] = acc * (1.0f / 128.0f) + bh[0];
      }
    }
  }
}

extern "C" void kernel_launch(void* const* d_in, const int* in_sizes, int n_in,
                              void* d_out, int out_size, void* d_ws, size_t ws_size,
                              hipStream_t stream) {
  const float* xin = (const float*)d_in[0];   // node_features [512,128,128]
  const float* adj = (const float*)d_in[1];   // adj [512,128,128]
  const float* W1  = (const float*)d_in[2];
  const float* b1  = (const float*)d_in[3];
  const float* W2  = (const float*)d_in[4];
  const float* b2  = (const float*)d_in[5];
  const float* W3  = (const float*)d_in[6];
  const float* b3  = (const float*)d_in[7];
  const float* Wh  = (const float*)d_in[8];
  const float* bh  = (const float*)d_in[9];

  unsigned short* wt = (unsigned short*)d_ws;   // 327,680 B of bf16 W^T

  gnn_prep<<<256, 256, 0, stream>>>(W1, W2, W3, wt);
  gnn_main<<<512, 1024, 0, stream>>>(xin, adj, b1, b2, b3, Wh, bh, wt, (float*)d_out);
}

// Round 7
// 106.157 us; speedup vs baseline: 1.0764x; 1.0764x over previous
//
#include <hip/hip_runtime.h>
#include <hip/hip_bf16.h>

typedef __attribute__((ext_vector_type(8))) short bf16x8;   // 8 bf16 (MFMA A/B frag)
typedef __attribute__((ext_vector_type(4))) float f32x4;    // MFMA C/D frag

static __device__ __forceinline__ unsigned short f2b(float f) {
  union { __hip_bfloat16 h; unsigned short u; } cv;
  cv.h = __float2bfloat16(f);
  return cv.u;
}

static __device__ __forceinline__ bf16x8 pack8(float4 a, float4 b) {
  bf16x8 r;
  r[0] = (short)f2b(a.x); r[1] = (short)f2b(a.y); r[2] = (short)f2b(a.z); r[3] = (short)f2b(a.w);
  r[4] = (short)f2b(b.x); r[5] = (short)f2b(b.y); r[6] = (short)f2b(b.z); r[7] = (short)f2b(b.w);
  return r;
}

// ---- prep: weights -> bf16 W^T in ws ----
// wt layout (bf16 elems): WT1 @0 (256x128), WT2 @32768 (256x256), WT3 @98304 (256x256)
__global__ void __launch_bounds__(256) gnn_prep(const float* __restrict__ W1,
                                                const float* __restrict__ W2,
                                                const float* __restrict__ W3,
                                                unsigned short* __restrict__ wt) {
  int idx = blockIdx.x * 256 + threadIdx.x;   // 0..65535
  unsigned short* wt1 = wt;
  unsigned short* wt2 = wt + 32768;
  unsigned short* wt3 = wt + 98304;
  if (idx < 32768) { int d = idx >> 8, h = idx & 255; wt1[h * 128 + d] = f2b(W1[idx]); }
  { int d = idx >> 8, h = idx & 255; wt2[h * 256 + d] = f2b(W2[idx]); wt3[h * 256 + d] = f2b(W3[idx]); }
}

// ---- main: one block per graph, 1024 thr (16 waves), 128 KB LDS, 1 block/CU ----
// Full-layer phases (2 barriers/layer) with R5's proven spill-free register shape:
// A-phase processes d-tiles in batches of TWO (accA[2], a[2]); B-phase accB[2][4].
#define XS(d, colb) ((d) * 128 + ((((colb) ^ (((d) & 15) << 4))) >> 1))
#define AG2(i, colb) ((i) * 256 + ((((colb) ^ (((i) & 15) << 4))) >> 1))

__global__ void __launch_bounds__(1024, 4) gnn_main(
    const float* __restrict__ xin, const float* __restrict__ adjg,
    const float* __restrict__ b1, const float* __restrict__ b2,
    const float* __restrict__ b3, const float* __restrict__ Wh,
    const float* __restrict__ bh, const unsigned short* __restrict__ wt,
    float* __restrict__ out) {
  __shared__ unsigned short sXT[256 * 128];    // X^T [d][j], swizzled; 64 KB
  __shared__ unsigned short sAgg[128 * 256];   // AGG [i][d] full layer, swizzled; 64 KB

  const int g = blockIdx.x, tid = threadIdx.x;
  const int lane = tid & 63, w = tid >> 6;     // 16 waves
  const int l15 = lane & 15, l4 = lane >> 4;
  const int wm = w & 1;    // A-phase: d-half of this i-slice
  const int wi = w >> 1;   // A-phase: i-slice (0..7)
  const int wr = w & 3;    // B-phase: i-group (0..3)
  const int wc = w >> 2;   // B-phase: h-group (0..3)

  const float* xg = xin + (size_t)g * 16384;
  const float* ag = adjg + (size_t)g * 16384;

  // ---- adj B-fragments: wave covers i in [wi*16, wi*16+16); loaded once, 16 regs ----
  // (adjacency is layer-invariant AND symmetric: adj[j][i] read as rows adj[i][j])
  bf16x8 adjF[4];
  {
    int ir = wi * 16 + l15;
#pragma unroll
    for (int ks = 0; ks < 4; ++ks) {
      float4 a0 = *(const float4*)(ag + ir * 128 + ks * 32 + l4 * 8);
      float4 a1 = *(const float4*)(ag + ir * 128 + ks * 32 + l4 * 8 + 4);
      adjF[ks] = pack8(a0, a1);
    }
  }
  // ---- in-kernel X transpose: X[j][d] fp32 -> sXT[d][j] bf16 (4x4 register-blocked) ----
  {
    int db = tid & 31, jb = tid >> 5;          // 32 d-blocks x 32 j-blocks
    int d0 = db * 4, j0 = jb * 4;
    float4 r0 = *(const float4*)(xg + (j0 + 0) * 128 + d0);
    float4 r1 = *(const float4*)(xg + (j0 + 1) * 128 + d0);
    float4 r2 = *(const float4*)(xg + (j0 + 2) * 128 + d0);
    float4 r3 = *(const float4*)(xg + (j0 + 3) * 128 + d0);
    *(ushort4*)&sXT[XS(d0 + 0, j0 * 2)] = make_ushort4(f2b(r0.x), f2b(r1.x), f2b(r2.x), f2b(r3.x));
    *(ushort4*)&sXT[XS(d0 + 1, j0 * 2)] = make_ushort4(f2b(r0.y), f2b(r1.y), f2b(r2.y), f2b(r3.y));
    *(ushort4*)&sXT[XS(d0 + 2, j0 * 2)] = make_ushort4(f2b(r0.z), f2b(r1.z), f2b(r2.z), f2b(r3.z));
    *(ushort4*)&sXT[XS(d0 + 3, j0 * 2)] = make_ushort4(f2b(r0.w), f2b(r1.w), f2b(r2.w), f2b(r3.w));
  }
  __syncthreads();

  for (int l = 0; l < 3; ++l) {
    const int Din = (l == 0) ? 128 : 256;
    const int tpw = Din >> 5;                  // d-tiles per wave in A-phase (4 or 8)
    const unsigned short* wtl = (l == 0) ? wt : (l == 1) ? wt + 32768 : wt + 98304;

    // ---- phase A (full layer, NO interior barriers): AGG^T[d][i] = X^T A, K=128 ----
    // wave (wm,wi): d-tiles wm*tpw + [0,tpw), batches of 2 (R5's spill-free shape)
    for (int b = 0; b < (tpw >> 1); ++b) {
      f32x4 accA[2];
      accA[0] = (f32x4){0.f, 0.f, 0.f, 0.f};
      accA[1] = (f32x4){0.f, 0.f, 0.f, 0.f};
#pragma unroll
      for (int ks = 0; ks < 4; ++ks) {
        bf16x8 a[2];
#pragma unroll
        for (int t = 0; t < 2; ++t) {
          int dr = (wm * tpw + b * 2 + t) * 16 + l15;
          a[t] = *(const bf16x8*)&sXT[XS(dr, ks * 64 + l4 * 16)];
        }
#pragma unroll
        for (int t = 0; t < 2; ++t)
          accA[t] = __builtin_amdgcn_mfma_f32_16x16x32_bf16(a[t], adjF[ks], accA[t], 0, 0, 0);
      }
      int i = wi * 16 + l15;
#pragma unroll
      for (int t = 0; t < 2; ++t) {
        int dloc = (wm * tpw + b * 2 + t) * 16 + l4 * 4;
        f32x4 v = accA[t];
        *(ushort4*)&sAgg[AG2(i, 2 * dloc)] =
            make_ushort4(f2b(v[0]), f2b(v[1]), f2b(v[2]), f2b(v[3]));
      }
    }
    __syncthreads();

    // ---- phase B (full K, no interior barriers): H[i][h] = AGG[i][:] @ W[:][h] ----
    f32x4 accB[2][4];
#pragma unroll
    for (int mi = 0; mi < 2; ++mi)
#pragma unroll
      for (int ni = 0; ni < 4; ++ni) accB[mi][ni] = (f32x4){0.f, 0.f, 0.f, 0.f};

    for (int ks = 0; ks < (Din >> 5); ++ks) {
      bf16x8 aB[2];
#pragma unroll
      for (int mi = 0; mi < 2; ++mi) {
        int ir = wr * 32 + mi * 16 + l15;
        aB[mi] = *(const bf16x8*)&sAgg[AG2(ir, ks * 64 + l4 * 16)];
      }
#pragma unroll
      for (int ni = 0; ni < 4; ++ni) {
        int hr = wc * 64 + ni * 16 + l15;
        bf16x8 wf = *(const bf16x8*)(wtl + hr * Din + ks * 32 + l4 * 8);
#pragma unroll
        for (int mi = 0; mi < 2; ++mi)
          accB[mi][ni] = __builtin_amdgcn_mfma_f32_16x16x32_bf16(aB[mi], wf, accB[mi][ni], 0, 0, 0);
      }
    }

    if (l < 2) {
      const float* bl = (l == 0) ? b1 : b2;
      // H[i][h] -> sXT[h][i] (next layer's X^T), 8B swizzled writes
      // (safe: all sXT reads finished before the post-A barrier)
#pragma unroll
      for (int ni = 0; ni < 4; ++ni) {
        int h = wc * 64 + ni * 16 + l15;
        float bias = bl[h];
#pragma unroll
        for (int mi = 0; mi < 2; ++mi) {
          int i0 = wr * 32 + mi * 16 + l4 * 4;
          f32x4 v = accB[mi][ni];
          *(ushort4*)&sXT[XS(h, 2 * i0)] = make_ushort4(
              f2b(fmaxf(v[0] + bias, 0.f)), f2b(fmaxf(v[1] + bias, 0.f)),
              f2b(fmaxf(v[2] + bias, 0.f)), f2b(fmaxf(v[3] + bias, 0.f)));
        }
      }
      __syncthreads();
    } else {
      // ---- mean pool + linear head (fp32) ----
      __syncthreads();                // all waves done READING sAgg before aliasing it
      float* sPool = (float*)sAgg;    // [4 wr][256 h]
      float ps[4];
#pragma unroll
      for (int ni = 0; ni < 4; ++ni) {
        float bias = b3[wc * 64 + ni * 16 + l15];
        float s = 0.f;
#pragma unroll
        for (int mi = 0; mi < 2; ++mi)
#pragma unroll
          for (int r = 0; r < 4; ++r) s += fmaxf(accB[mi][ni][r] + bias, 0.f);
        s += __shfl_xor(s, 16);   // reduce over l4 bit 0
        s += __shfl_xor(s, 32);   // reduce over l4 bit 1
        ps[ni] = s;
      }
      if (l4 == 0) {
#pragma unroll
        for (int ni = 0; ni < 4; ++ni)
          sPool[wr * 256 + wc * 64 + ni * 16 + l15] = ps[ni];
      }
      __syncthreads();
      if (w == 0) {
        float acc = 0.f;
#pragma unroll
        for (int q = 0; q < 4; ++q) {
          int h = lane + q * 64;
          float p = sPool[h] + sPool[256 + h] + sPool[512 + h] + sPool[768 + h];
          acc += p * Wh[h];
        }
#pragma unroll
        for (int off = 32; off > 0; off >>= 1) acc += __shfl_xor(acc, off);
        if (lane == 0) out[g] = acc * (1.0f / 128.0f) + bh[0];
      }
    }
  }
}

extern "C" void kernel_launch(void* const* d_in, const int* in_sizes, int n_in,
                              void* d_out, int out_size, void* d_ws, size_t ws_size,
                              hipStream_t stream) {
  const float* xin = (const float*)d_in[0];   // node_features [512,128,128]
  const float* adj = (const float*)d_in[1];   // adj [512,128,128]
  const float* W1  = (const float*)d_in[2];
  const float* b1  = (const float*)d_in[3];
  const float* W2  = (const float*)d_in[4];
  const float* b2  = (const float*)d_in[5];
  const float* W3  = (const float*)d_in[6];
  const float* b3  = (const float*)d_in[7];
  const float* Wh  = (const float*)d_in[8];
  const float* bh  = (const float*)d_in[9];

  unsigned short* wt = (unsigned short*)d_ws;   // 327,680 B of bf16 W^T

  gnn_prep<<<256, 256, 0, stream>>>(W1, W2, W3, wt);
  gnn_main<<<512, 1024, 0, stream>>>(xin, adj, b1, b2, b3, Wh, bh, wt, (float*)d_out);
}

// Round 8
// 76.775 us; speedup vs baseline: 1.4884x; 1.3827x over previous
//
#include <hip/hip_runtime.h>
#include <hip/hip_bf16.h>

typedef __attribute__((ext_vector_type(8))) short bf16x8;   // 8 bf16 (MFMA A/B frag)
typedef __attribute__((ext_vector_type(4))) float f32x4;    // MFMA C/D frag

static __device__ __forceinline__ unsigned short f2b(float f) {
  union { __hip_bfloat16 h; unsigned short u; } cv;
  cv.h = __float2bfloat16(f);
  return cv.u;
}

static __device__ __forceinline__ bf16x8 pack8(float4 a, float4 b) {
  bf16x8 r;
  r[0] = (short)f2b(a.x); r[1] = (short)f2b(a.y); r[2] = (short)f2b(a.z); r[3] = (short)f2b(a.w);
  r[4] = (short)f2b(b.x); r[5] = (short)f2b(b.y); r[6] = (short)f2b(b.z); r[7] = (short)f2b(b.w);
  return r;
}

// ---- prep: weights -> bf16 W^T in ws ----
// wt layout (bf16): WT1 @0 (256x128), WT2 @32768 (256x256), WT3 @98304 (256x256)
__global__ void __launch_bounds__(256) gnn_prep(const float* __restrict__ W1,
                                                const float* __restrict__ W2,
                                                const float* __restrict__ W3,
                                                unsigned short* __restrict__ wt) {
  int idx = blockIdx.x * 256 + threadIdx.x;   // 0..65535
  unsigned short* wt1 = wt;
  unsigned short* wt2 = wt + 32768;
  unsigned short* wt3 = wt + 98304;
  if (idx < 32768) { int d = idx >> 8, h = idx & 255; wt1[h * 128 + d] = f2b(W1[idx]); }
  { int d = idx >> 8, h = idx & 255; wt2[h * 256 + d] = f2b(W2[idx]); wt3[h * 256 + d] = f2b(W3[idx]); }
}

// ---- main: 1 block/graph, 1024 thr (16 waves), 128 KB LDS ----
// Layer = two all-LDS/reg GEMMs, zero transposes:
//  phase1: T[i][h] = X[i][:] @ WT[h][:]   (A=sX rows, B=sW rows; D col=h -> writes T^T[h][i] 8B-contig)
//  phase2: H via D[m=h][n=i] = T^T[h][:] @ adj[i][:] (A=sT rows, B=adjF regs; D col=i -> writes sX[i][h] 8B-contig)
// sW = 2 x 32KB k-chunk buffers ALIASED over sT (sT written only after phase1's k-loop).
// Swizzles: 16B-granule XOR by low row bits; identical on write+read; reads are <=2-way (free).
#define SX(i, colb) ((i) * 256 + ((((colb) ^ (((i) & 15) << 4))) >> 1))   // pitch 512B
#define ST(h, colb) ((h) * 128 + ((((colb) ^ (((h) & 15) << 4))) >> 1))   // pitch 256B
#define SWI(h, gr) ((h) * 64 + (((gr) ^ ((h) & 7)) << 3))                 // pitch 128B, granule slots

__global__ void __launch_bounds__(1024, 4) gnn_main(
    const float* __restrict__ xin, const float* __restrict__ adjg,
    const float* __restrict__ b1, const float* __restrict__ b2,
    const float* __restrict__ b3, const float* __restrict__ Wh,
    const float* __restrict__ bh, const unsigned short* __restrict__ wt,
    float* __restrict__ out) {
  __shared__ unsigned short sX[128 * 256];   // X [i][d] natural, swizzled; 64 KB
  __shared__ unsigned short sT[256 * 128];   // T^T [h][i], swizzled; 64 KB (also hosts sW dbuf + pool)

  const int g = blockIdx.x, tid = threadIdx.x;
  const int lane = tid & 63, w = tid >> 6;   // 16 waves
  const int l15 = lane & 15, l4 = lane >> 4;
  const int wi = w & 3;    // i-group: 32 i (2 tiles)
  const int wh = w >> 2;   // h-group: 64 h (4 tiles)

  const float* xg = xin + (size_t)g * 16384;
  const float* ag = adjg + (size_t)g * 16384;

  // ---- adj B-fragments [n=i][k=j]: natural adj rows; loaded once, 32 regs ----
  bf16x8 adjF[2][4];
#pragma unroll
  for (int nt = 0; nt < 2; ++nt) {
    int ir = wi * 32 + nt * 16 + l15;
#pragma unroll
    for (int ks = 0; ks < 4; ++ks) {
      float4 a0 = *(const float4*)(ag + ir * 128 + ks * 32 + l4 * 8);
      float4 a1 = *(const float4*)(ag + ir * 128 + ks * 32 + l4 * 8 + 4);
      adjF[nt][ks] = pack8(a0, a1);
    }
  }
  // ---- stage X natural [i][d] fp32->bf16 (straight copy, no transpose) ----
  {
    int i = tid >> 3, e0 = (tid & 7) * 16;   // 16 fp32 per thread
    float4 r0 = *(const float4*)(xg + i * 128 + e0);
    float4 r1 = *(const float4*)(xg + i * 128 + e0 + 4);
    float4 r2 = *(const float4*)(xg + i * 128 + e0 + 8);
    float4 r3 = *(const float4*)(xg + i * 128 + e0 + 12);
    *(bf16x8*)&sX[SX(i, e0 * 2)] = pack8(r0, r1);
    *(bf16x8*)&sX[SX(i, e0 * 2 + 16)] = pack8(r2, r3);
  }
  __syncthreads();

  for (int l = 0; l < 3; ++l) {
    const int Din = (l == 0) ? 128 : 256;
    const int nkc = Din >> 6;                // 64-wide k-chunks
    const unsigned short* wtl = (l == 0) ? wt : (l == 1) ? wt + 32768 : wt + 98304;

    // ---- phase 1: accT[it][ht] over k-chunks; W dbuf-staged into sT region ----
    f32x4 accT[2][4];
#pragma unroll
    for (int it = 0; it < 2; ++it)
#pragma unroll
      for (int ht = 0; ht < 4; ++ht) accT[it][ht] = (f32x4){0.f, 0.f, 0.f, 0.f};

    bf16x8 stg0, stg1;
    // prologue: stage chunk 0 into buf 0
    stg0 = *(const bf16x8*)(wtl + (tid >> 3) * Din + (tid & 7) * 8);
    stg1 = *(const bf16x8*)(wtl + (128 + (tid >> 3)) * Din + (tid & 7) * 8);
    *(bf16x8*)&sT[SWI(tid >> 3, tid & 7)] = stg0;
    *(bf16x8*)&sT[SWI(128 + (tid >> 3), tid & 7)] = stg1;
    __syncthreads();

    for (int kc = 0; kc < nkc; ++kc) {
      if (kc + 1 < nkc) {                    // issue next-chunk loads early (latency under compute)
        const unsigned short* src = wtl + (kc + 1) * 64;
        stg0 = *(const bf16x8*)(src + (tid >> 3) * Din + (tid & 7) * 8);
        stg1 = *(const bf16x8*)(src + (128 + (tid >> 3)) * Din + (tid & 7) * 8);
      }
      const unsigned short* sW = sT + (kc & 1) * 16384;
#pragma unroll
      for (int ks2 = 0; ks2 < 2; ++ks2) {
        bf16x8 ax[2], bw[4];
#pragma unroll
        for (int it = 0; it < 2; ++it) {
          int i = wi * 32 + it * 16 + l15;
          ax[it] = *(const bf16x8*)&sX[SX(i, kc * 128 + ks2 * 64 + l4 * 16)];
        }
#pragma unroll
        for (int ht = 0; ht < 4; ++ht) {
          int h = wh * 64 + ht * 16 + l15;
          bw[ht] = *(const bf16x8*)&sW[SWI(h, ks2 * 4 + l4)];
        }
#pragma unroll
        for (int it = 0; it < 2; ++it)
#pragma unroll
          for (int ht = 0; ht < 4; ++ht)
            accT[it][ht] = __builtin_amdgcn_mfma_f32_16x16x32_bf16(ax[it], bw[ht], accT[it][ht], 0, 0, 0);
      }
      if (kc + 1 < nkc) {                    // write next chunk to other buf (its readers done pre-loop)
        unsigned short* dst = sT + ((kc + 1) & 1) * 16384;
        *(bf16x8*)&dst[SWI(tid >> 3, tid & 7)] = stg0;
        *(bf16x8*)&dst[SWI(128 + (tid >> 3), tid & 7)] = stg1;
      }
      __syncthreads();
    }

    // ---- write T^T[h][i] (overwrites sW bufs; all reads done) ----
#pragma unroll
    for (int it = 0; it < 2; ++it)
#pragma unroll
      for (int ht = 0; ht < 4; ++ht) {
        int h = wh * 64 + ht * 16 + l15;
        int i0 = wi * 32 + it * 16 + l4 * 4;
        f32x4 v = accT[it][ht];
        *(ushort4*)&sT[ST(h, 2 * i0)] =
            make_ushort4(f2b(v[0]), f2b(v[1]), f2b(v[2]), f2b(v[3]));
      }
    __syncthreads();

    // ---- phase 2: D[m=h][n=i] = T^T[h][:] @ adj[i][:] ; all-LDS/reg, 8 accs ----
    f32x4 accH[4][2];
#pragma unroll
    for (int mt = 0; mt < 4; ++mt)
#pragma unroll
      for (int nt = 0; nt < 2; ++nt) accH[mt][nt] = (f32x4){0.f, 0.f, 0.f, 0.f};
#pragma unroll
    for (int ks = 0; ks < 4; ++ks) {
      bf16x8 aT[4];
#pragma unroll
      for (int mt = 0; mt < 4; ++mt) {
        int h = wh * 64 + mt * 16 + l15;
        aT[mt] = *(const bf16x8*)&sT[ST(h, ks * 64 + l4 * 16)];
      }
#pragma unroll
      for (int mt = 0; mt < 4; ++mt)
#pragma unroll
        for (int nt = 0; nt < 2; ++nt)
          accH[mt][nt] = __builtin_amdgcn_mfma_f32_16x16x32_bf16(aT[mt], adjF[nt][ks], accH[mt][nt], 0, 0, 0);
    }

    if (l < 2) {
      // H -> next X: write sX[i][h] (col=i fixed/lane, h-quad contiguous 8B)
      const float* bl = (l == 0) ? b1 : b2;
#pragma unroll
      for (int mt = 0; mt < 4; ++mt) {
        int h0 = wh * 64 + mt * 16 + l4 * 4;
        float4 bias = *(const float4*)(bl + h0);
#pragma unroll
        for (int nt = 0; nt < 2; ++nt) {
          int i = wi * 32 + nt * 16 + l15;
          f32x4 v = accH[mt][nt];
          *(ushort4*)&sX[SX(i, 2 * h0)] = make_ushort4(
              f2b(fmaxf(v[0] + bias.x, 0.f)), f2b(fmaxf(v[1] + bias.y, 0.f)),
              f2b(fmaxf(v[2] + bias.z, 0.f)), f2b(fmaxf(v[3] + bias.w, 0.f)));
        }
      }
      __syncthreads();
    } else {
      // ---- mean pool over i + linear head ----
      float ps[4][4];                        // [mt][r], lane's 4 h per tile
#pragma unroll
      for (int mt = 0; mt < 4; ++mt) {
        int h0 = wh * 64 + mt * 16 + l4 * 4;
        float4 bias = *(const float4*)(b3 + h0);
#pragma unroll
        for (int r = 0; r < 4; ++r) {
          float bb = (r == 0) ? bias.x : (r == 1) ? bias.y : (r == 2) ? bias.z : bias.w;
          float s = fmaxf(accH[mt][0][r] + bb, 0.f) + fmaxf(accH[mt][1][r] + bb, 0.f);
          s += __shfl_xor(s, 1); s += __shfl_xor(s, 2);
          s += __shfl_xor(s, 4); s += __shfl_xor(s, 8);   // sum over 16 i (l15 group)
          ps[mt][r] = s;
        }
      }
      __syncthreads();                       // all sT reads done before aliasing as pool
      float* sPool = (float*)sT;             // [4 wi][256 h]
      if (l15 == 0) {
#pragma unroll
        for (int mt = 0; mt < 4; ++mt)
#pragma unroll
          for (int r = 0; r < 4; ++r)
            sPool[wi * 256 + wh * 64 + mt * 16 + l4 * 4 + r] = ps[mt][r];
      }
      __syncthreads();
      if (w == 0) {
        float acc = 0.f;
#pragma unroll
        for (int q = 0; q < 4; ++q) {
          int h = lane + q * 64;
          float p = sPool[h] + sPool[256 + h] + sPool[512 + h] + sPool[768 + h];
          acc += p * Wh[h];
        }
#pragma unroll
        for (int off = 32; off > 0; off >>= 1) acc += __shfl_xor(acc, off);
        if (lane == 0) out[g] = acc * (1.0f / 128.0f) + bh[0];
      }
    }
  }
}

extern "C" void kernel_launch(void* const* d_in, const int* in_sizes, int n_in,
                              void* d_out, int out_size, void* d_ws, size_t ws_size,
                              hipStream_t stream) {
  const float* xin = (const float*)d_in[0];   // node_features [512,128,128]
  const float* adj = (const float*)d_in[1];   // adj [512,128,128]
  const float* W1  = (const float*)d_in[2];
  const float* b1  = (const float*)d_in[3];
  const float* W2  = (const float*)d_in[4];
  const float* b2  = (const float*)d_in[5];
  const float* W3  = (const float*)d_in[6];
  const float* b3  = (const float*)d_in[7];
  const float* Wh  = (const float*)d_in[8];
  const float* bh  = (const float*)d_in[9];

  unsigned short* wt = (unsigned short*)d_ws;   // 327,680 B of bf16 W^T

  gnn_prep<<<256, 256, 0, stream>>>(W1, W2, W3, wt);
  gnn_main<<<512, 1024, 0, stream>>>(xin, adj, b1, b2, b3, Wh, bh, wt, (float*)d_out);
}